// Round 3
// baseline (665.571 us; speedup 1.0000x reference)
//
#include <hip/hip_runtime.h>

#define NCLS 128
#define CM_ELEMS (NCLS * NCLS)

// ---------------------------------------------------------------------------
// Kernel 1: zero the confusion matrix (d_ws is poisoned 0xAA before every call)
// ---------------------------------------------------------------------------
__global__ void zero_cm_kernel(int* __restrict__ cm) {
    int i = blockIdx.x * blockDim.x + threadIdx.x;
    if (i < CM_ELEMS) cm[i] = 0;
}

// ---------------------------------------------------------------------------
// Kernel 2: per-row argmax (128 fp32) + histogram into cm[t*128 + p].
// Layout: block = 256 threads = 4 waves; each HALF-wave (32 lanes) owns one
// row per iteration. Lane reads float4 (16 B) -> 32 lanes * 16 B = one full
// 512 B row, coalesced; a wave covers 2 consecutive rows = 1024 B.
// Argmax reduce: 5-step shfl_xor butterfly over the 32-lane half, with
// first-index tie-break to match jnp.argmax semantics.
// ---------------------------------------------------------------------------
__global__ __launch_bounds__(256) void argmax_hist_kernel(
        const float* __restrict__ y_pred,
        const int*   __restrict__ y_true,
        int*         __restrict__ cm,
        int N) {
    const int lane = threadIdx.x & 63;       // lane in wave
    const int wid  = threadIdx.x >> 6;       // wave in block (0..3)
    const int half = lane >> 5;              // which half-wave (0/1)
    const int l32  = lane & 31;              // lane within half-wave

    // rows per block per pass = 4 waves * 2 rows = 8
    long long row = (long long)blockIdx.x * 8 + wid * 2 + half;
    const long long stride = (long long)gridDim.x * 8;

    for (; row < N; row += stride) {
        const float4 v = *reinterpret_cast<const float4*>(
            y_pred + row * (long long)NCLS + l32 * 4);

        // local argmax over 4 elems, prefer lower index on ties
        float bv = v.x; int bi = l32 * 4;
        if (v.y > bv) { bv = v.y; bi = l32 * 4 + 1; }
        if (v.z > bv) { bv = v.z; bi = l32 * 4 + 2; }
        if (v.w > bv) { bv = v.w; bi = l32 * 4 + 3; }

        // butterfly reduce across the 32-lane half (masks < 32 stay in-half)
        #pragma unroll
        for (int m = 1; m <= 16; m <<= 1) {
            float ov = __shfl_xor(bv, m, 64);
            int   oi = __shfl_xor(bi, m, 64);
            if (ov > bv || (ov == bv && oi < bi)) { bv = ov; bi = oi; }
        }

        if (l32 == 0) {
            int t = y_true[row];
            atomicAdd(&cm[t * NCLS + bi], 1);   // device-scope by default
        }
    }
}

// ---------------------------------------------------------------------------
// Kernel 3: F1 from the confusion matrix. One block, 128 threads; thread c
// owns class c. Counts sum to <= 1e6 < 2^24 so f32 accumulation is exact.
// f1 = 2pr/(p+r+eps) is symmetric in p,r so row/col swap in the reference
// is irrelevant.
// ---------------------------------------------------------------------------
__global__ void f1_reduce_kernel(const int* __restrict__ cm,
                                 float* __restrict__ out) {
    __shared__ float partial[2];
    const int c = threadIdx.x;               // 0..127

    float rowsum = 0.0f, colsum = 0.0f;
    #pragma unroll 4
    for (int j = 0; j < NCLS; ++j) {
        rowsum += (float)cm[c * NCLS + j];
        colsum += (float)cm[j * NCLS + c];
    }
    const float d = (float)cm[c * NCLS + c];

    const float p  = d / (rowsum + 1e-12f);
    const float r  = d / (colsum + 1e-12f);
    float f1 = 2.0f * p * r / (p + r + 1e-12f);

    // reduce 128 f1 values: wave butterfly + 2-wave LDS combine
    #pragma unroll
    for (int m = 1; m < 64; m <<= 1) f1 += __shfl_xor(f1, m, 64);
    if ((threadIdx.x & 63) == 0) partial[threadIdx.x >> 6] = f1;
    __syncthreads();
    if (threadIdx.x == 0) out[0] = (partial[0] + partial[1]) * (1.0f / NCLS);
}

// ---------------------------------------------------------------------------
extern "C" void kernel_launch(void* const* d_in, const int* in_sizes, int n_in,
                              void* d_out, int out_size, void* d_ws, size_t ws_size,
                              hipStream_t stream) {
    const float* y_pred = (const float*)d_in[0];
    const int*   y_true = (const int*)d_in[1];   // harness delivers ints as int32
    const int N = in_sizes[1];                   // 1,000,000 rows

    int*   cm  = (int*)d_ws;                     // 128*128*4 = 64 KB scratch
    float* out = (float*)d_out;

    zero_cm_kernel<<<(CM_ELEMS + 255) / 256, 256, 0, stream>>>(cm);

    // memory-bound: cap grid ~2048 blocks, grid-stride the rest (G11)
    const int grid = 2048;
    argmax_hist_kernel<<<grid, 256, 0, stream>>>(y_pred, y_true, cm, N);

    f1_reduce_kernel<<<1, NCLS, 0, stream>>>(cm, out);
}